// Round 4
// baseline (101.382 us; speedup 1.0000x reference)
//
#include <hip/hip_runtime.h>
#include <hip/hip_bf16.h>

// LowRankBilinearPooling: out[b,o] = (sum_i relu(x1 W1))_h * (sum_j relu(x2 W2))_h @ Wp + bp*196^2
// B=16, N=196, C=768, H=512, O=128. fp32 in/out; bf16 MFMA inside.
// Pipeline: pretile (W and X -> bf16 in gemm-LDS order) -> gemm+relu+rowsum -> proj.

#define NB 16
#define NROW 196
#define KC_ 768
#define HH 512
#define OO 128

using short8 = __attribute__((ext_vector_type(8))) short;
using f32x16 = __attribute__((ext_vector_type(16))) float;

__device__ __forceinline__ short2 pk2bf(float a, float b) {
    // v_cvt_pk_bf16_f32 on gfx950
    __hip_bfloat162 h = __float22bfloat162_rn(make_float2(a, b));
    union { __hip_bfloat162 h; short2 s; } u; u.h = h;
    return u.s;
}

// Prepass, 160 blocks x 256 thr.
// Blocks 0..95: W-tile. Wt plane (branch*4+ht)*12+kc, unit (p,col) = bf16 of
//   W[(kc*64+p*8+j)*512 + ht*128 + col], j=0..7.
// Blocks 96..159: X-tile. Xt plane ((branch*16+b)*2+mh)*12+kc, unit (p,row) =
//   bf16 of x[b][mh*128+row][kc*64+p*8+j], rows >=196 zeroed.
__global__ __launch_bounds__(256)
void pretile(const float* __restrict__ x1, const float* __restrict__ x2,
             const float* __restrict__ W1, const float* __restrict__ W2,
             unsigned short* __restrict__ Wt, unsigned short* __restrict__ Xt) {
    const int t = threadIdx.x;
    if (blockIdx.x < 96) {
        const int bb = blockIdx.x;              // branch*48 + ht*12 + kc
        const int branch = bb / 48;
        const int rem = bb % 48;
        const int ht = rem / 12;
        const int kc = rem % 12;
        const float* __restrict__ W = branch ? W2 : W1;
        unsigned short* __restrict__ out = Wt + (size_t)bb * 8192;
#pragma unroll
        for (int i = 0; i < 4; ++i) {
            const int u = i * 256 + t;
            const int p = u >> 7, col = u & 127;
            const float* src = W + (kc * 64 + p * 8) * HH + ht * 128 + col;
            float f[8];
#pragma unroll
            for (int j = 0; j < 8; ++j) f[j] = src[j * HH];   // lanes walk col: coalesced
            short8 v; short2 s;
#pragma unroll
            for (int j = 0; j < 4; ++j) {
                s = pk2bf(f[2 * j], f[2 * j + 1]); v[2 * j] = s.x; v[2 * j + 1] = s.y;
            }
            *(short8*)(out + u * 8) = v;
        }
    } else {
        const int xb = blockIdx.x - 96;         // branch*32 + b*2 + mh
        const int branch = xb >> 5;
        const int b  = (xb & 31) >> 1;
        const int mh = xb & 1;
        const float* __restrict__ x = branch ? x2 : x1;
        unsigned short* __restrict__ outb =
            Xt + (size_t)(((branch * 16 + b) * 2 + mh) * 12) * 8192;
#pragma unroll 1
        for (int kc = 0; kc < 12; ++kc) {
            unsigned short* __restrict__ out = outb + kc * 8192;
#pragma unroll
            for (int h = 0; h < 2; ++h) {
                const int v = h * 256 + t;       // (row, g): g = 16-k group
                const int row = v >> 2, g = v & 3;
                const int r_abs = mh * 128 + row;
                float4 f0, f1;
                if (r_abs < NROW) {
                    const float* src = x + ((size_t)(b * NROW + r_abs)) * KC_ + kc * 64 + g * 16;
                    f0 = *(const float4*)(src);      // lanes: g0..3 then row++ -> coalesced 64B/lane
                    f1 = *(const float4*)(src + 4);
                    float4 f2 = *(const float4*)(src + 8);
                    float4 f3 = *(const float4*)(src + 12);
                    short8 v0, v1; short2 s;
                    s = pk2bf(f0.x, f0.y); v0[0] = s.x; v0[1] = s.y;
                    s = pk2bf(f0.z, f0.w); v0[2] = s.x; v0[3] = s.y;
                    s = pk2bf(f1.x, f1.y); v0[4] = s.x; v0[5] = s.y;
                    s = pk2bf(f1.z, f1.w); v0[6] = s.x; v0[7] = s.y;
                    s = pk2bf(f2.x, f2.y); v1[0] = s.x; v1[1] = s.y;
                    s = pk2bf(f2.z, f2.w); v1[2] = s.x; v1[3] = s.y;
                    s = pk2bf(f3.x, f3.y); v1[4] = s.x; v1[5] = s.y;
                    s = pk2bf(f3.z, f3.w); v1[6] = s.x; v1[7] = s.y;
                    *(short8*)(out + ((2 * g + 0) * 128 + row) * 8) = v0;
                    *(short8*)(out + ((2 * g + 1) * 128 + row) * 8) = v1;
                } else {
                    short8 z = {};
                    *(short8*)(out + ((2 * g + 0) * 128 + row) * 8) = z;
                    *(short8*)(out + ((2 * g + 1) * 128 + row) * 8) = z;
                }
            }
        }
    }
}

// Kernel 1: fused GEMM + relu + row-sum.
// Grid: 256 blocks = 2(branch) x 16(b) x 4(ht) x 2(mh). Block: 512 thr = 8 waves
// = (mp 0..3: 32-row tile) x (sp 0..1: 64-col strip). K chunked by 64,
// double-buffered LDS, one barrier per chunk, register-staged prefetch dist 2.
// All staging is bf16 short8 loads from pre-tiled Xt/Wt: no cvt, no bounds.
__global__ __launch_bounds__(512, 1)
void gemm_relu_rowsum(const unsigned short* __restrict__ Xt,
                      const unsigned short* __restrict__ Wt,
                      float* __restrict__ sbuf) {
    __shared__ unsigned short Alds[2][8192];   // [k8(8)][row(128)][8] per buf
    __shared__ unsigned short Blds[2][8192];
    __shared__ float psum[16 * 32];

    const int bid = blockIdx.x;
    const int p  = bid & 31;           // (branch,b): tiles of same x[b] share an XCD
    const int tt = bid >> 5;
    const int branch = p >> 4;
    const int b      = p & 15;
    const int ht = tt >> 1;
    const int mh = tt & 1;

    const unsigned short* __restrict__ Xc =
        Xt + (size_t)(((branch * 16 + b) * 2 + mh) * 12) * 8192;
    const unsigned short* __restrict__ Wc =
        Wt + (size_t)((branch * 4 + ht) * 12) * 8192;

    const int t = threadIdx.x;

    short8 a0r, a1r, b0r, b1r;
    auto load_stage = [&](int kc) {
        const unsigned short* xc = Xc + kc * 8192;
        const unsigned short* wc = Wc + kc * 8192;
        a0r = *(const short8*)(xc + t * 8);            // units t and t+512: coalesced
        a1r = *(const short8*)(xc + (t + 512) * 8);
        b0r = *(const short8*)(wc + t * 8);
        b1r = *(const short8*)(wc + (t + 512) * 8);
    };
    auto write_stage = [&](int buf) {
        *(short8*)&Alds[buf][t * 8]          = a0r;    // lane-contiguous: conflict-free
        *(short8*)&Alds[buf][(t + 512) * 8]  = a1r;
        *(short8*)&Blds[buf][t * 8]          = b0r;
        *(short8*)&Blds[buf][(t + 512) * 8]  = b1r;
    };

    const int w  = t >> 6;
    const int l  = t & 63;
    const int m  = l & 31;
    const int q  = l >> 5;
    const int sp = w & 1;              // 64-col strip
    const int mp = w >> 1;             // 32-row tile
    const int aoff = (mp * 32 + m) * 8;
    const int boff = (sp * 64 + m) * 8;

    f32x16 acc0 = {}, acc1 = {};

    load_stage(0);
    write_stage(0);
    load_stage(1);
    __syncthreads();

#pragma unroll 1
    for (int kc = 0; kc < 12; ++kc) {
        const int pb = kc & 1;
#pragma unroll
        for (int ks = 0; ks < 4; ++ks) {
            const int base = (ks * 2 + q) * 1024;
            short8 af = *(const short8*)&Alds[pb][base + aoff];
            short8 b0 = *(const short8*)&Blds[pb][base + boff];
            short8 b1 = *(const short8*)&Blds[pb][base + boff + 256];
            acc0 = __builtin_amdgcn_mfma_f32_32x32x16_bf16(af, b0, acc0, 0, 0, 0);
            acc1 = __builtin_amdgcn_mfma_f32_32x32x16_bf16(af, b1, acc1, 0, 0, 0);
        }
        if (kc < 11) write_stage(1 - pb);   // chunk kc+1 -> other buffer
        if (kc < 10) load_stage(kc + 2);    // regs: stays in flight across barrier
        __syncthreads();                    // one barrier per chunk
    }

    // relu + sum over rows. C layout: col = lane&31 (m101); lanes l and l^32's
    // 16 regs together cover all 32 rows, order irrelevant for a sum.
    float cs0 = 0.f, cs1 = 0.f;
#pragma unroll
    for (int r = 0; r < 16; ++r) {
        cs0 += fmaxf(acc0[r], 0.f);
        cs1 += fmaxf(acc1[r], 0.f);
    }
    cs0 += __shfl_xor(cs0, 32);
    cs1 += __shfl_xor(cs1, 32);
    if (l < 32) {
        psum[((sp * 2 + 0) * 4 + mp) * 32 + l] = cs0;  // col tile 2sp
        psum[((sp * 2 + 1) * 4 + mp) * 32 + l] = cs1;  // col tile 2sp+1
    }
    __syncthreads();
    if (t < 128) {
        const int ct = t >> 5;
        const int cl = t & 31;
        float v = 0.f;
#pragma unroll
        for (int mp2 = 0; mp2 < 4; ++mp2)
            v += psum[(ct * 4 + mp2) * 32 + cl];
        sbuf[((branch * 2 + mh) * NB + b) * HH + ht * 128 + t] = v;
    }
}

// Kernel 2: out[b,o] = sum_h (s1[b,h]*s2[b,h]) * Wp[h,o] + bp[o]*196^2
__global__ __launch_bounds__(512)
void proj_kernel(const float* __restrict__ sbuf, const float* __restrict__ Wp,
                 const float* __restrict__ bp, float* __restrict__ out) {
    __shared__ float spl[HH];
    __shared__ float red[4][OO];
    const int b = blockIdx.x, t = threadIdx.x;
    {
        const float s1 = sbuf[(0 * NB + b) * HH + t] + sbuf[(1 * NB + b) * HH + t];
        const float s2 = sbuf[(2 * NB + b) * HH + t] + sbuf[(3 * NB + b) * HH + t];
        spl[t] = s1 * s2;
    }
    __syncthreads();
    const int to = t & 127, hq = t >> 7;
    float acc = 0.f;
#pragma unroll 8
    for (int h = hq * 128; h < hq * 128 + 128; ++h)
        acc += spl[h] * Wp[h * OO + to];
    red[hq][to] = acc;
    __syncthreads();
    if (t < OO)
        out[b * OO + t] = red[0][t] + red[1][t] + red[2][t] + red[3][t]
                        + bp[t] * 38416.0f;   // 196*196
}

extern "C" void kernel_launch(void* const* d_in, const int* in_sizes, int n_in,
                              void* d_out, int out_size, void* d_ws, size_t ws_size,
                              hipStream_t stream) {
    const float* x1 = (const float*)d_in[0];
    const float* x2 = (const float*)d_in[1];
    const float* W1 = (const float*)d_in[2];
    const float* W2 = (const float*)d_in[3];
    const float* Wp = (const float*)d_in[4];
    const float* bp = (const float*)d_in[5];
    float* sbuf = (float*)d_ws;                                    // 128 KB
    unsigned short* Wt = (unsigned short*)((char*)d_ws + (131072));            // 1.5 MB
    unsigned short* Xt = (unsigned short*)((char*)d_ws + (131072 + 1572864)); // 12.6 MB

    pretile<<<160, 256, 0, stream>>>(x1, x2, W1, W2, Wt, Xt);
    gemm_relu_rowsum<<<256, 512, 0, stream>>>(Xt, Wt, sbuf);
    proj_kernel<<<NB, 512, 0, stream>>>(sbuf, Wp, bp, (float*)d_out);
}